// Round 3
// baseline (65.391 us; speedup 1.0000x reference)
//
#include <hip/hip_runtime.h>
#include <math.h>

// TokenChoiceRouter: B=8, T=8192, D=512.
// d_out (float32 flat): [selected B*max_k][gate_weights B*max_k][raw_logits B*T][aux][z]
// max_k recovered host-side from out_size.

#define TT 8192
#define BB 8

// K1: one wave per token. 64 lanes x 8 floats = 512-dot, coalesced 2KB/wave.
__global__ __launch_bounds__(256) void logits_kernel(
    const float* __restrict__ x, const float* __restrict__ W,
    float* __restrict__ logits, int n_tokens)
{
    const int gid  = blockIdx.x * blockDim.x + threadIdx.x;
    const int wave = gid >> 6;
    const int lane = threadIdx.x & 63;
    if (wave >= n_tokens) return;

    const float4* xp = reinterpret_cast<const float4*>(x + (size_t)wave * 512 + lane * 8);
    const float4* wp = reinterpret_cast<const float4*>(W + lane * 8);
    float4 x0 = xp[0]; float4 x1 = xp[1];
    float4 w0 = wp[0]; float4 w1 = wp[1];

    // f64 accumulation keeps sign decisions aligned with the f64 numpy ref;
    // cost hidden under the HBM read.
    double acc = (double)x0.x * w0.x + (double)x0.y * w0.y
               + (double)x0.z * w0.z + (double)x0.w * w0.w
               + (double)x1.x * w1.x + (double)x1.y * w1.y
               + (double)x1.z * w1.z + (double)x1.w * w1.w;

    #pragma unroll
    for (int off = 32; off > 0; off >>= 1)
        acc += __shfl_xor(acc, off, 64);

    if (lane == 0) logits[wave] = (float)acc;
}

// K2: blocks 0..7 = per-row compaction/fill; block 8 = scalar losses.
__global__ __launch_bounds__(1024) void finish_kernel(
    const float* __restrict__ logits,
    float* __restrict__ out_sel, float* __restrict__ out_gw,
    float* __restrict__ out_aux, float* __restrict__ out_z, int max_k)
{
    const int tid  = threadIdx.x;
    const int lane = tid & 63;
    const int wid  = tid >> 6;          // 0..15

    if (blockIdx.x == BB) {
        // ---------- scalar losses from L2-resident logits ----------
        __shared__ float sred[1024];
        __shared__ float rowse[BB];
        for (int r = 0; r < BB; ++r) {
            const float* row = logits + (size_t)r * TT;
            float p = 0.f;
            for (int i = tid; i < TT; i += 1024) p += expf(row[i]);
            sred[tid] = p; __syncthreads();
            for (int s = 512; s > 0; s >>= 1) {
                if (tid < s) sred[tid] += sred[tid + s];
                __syncthreads();
            }
            if (tid == 0) rowse[r] = sred[0];
            __syncthreads();
        }
        float p = 0.f;
        for (int i = tid; i < BB * TT; i += 1024)
            p += 1.f / (1.f + expf(-logits[i]));
        sred[tid] = p; __syncthreads();
        for (int s = 512; s > 0; s >>= 1) {
            if (tid < s) sred[tid] += sred[tid + s];
            __syncthreads();
        }
        if (tid == 0) {
            float zz = 0.f;
            for (int r = 0; r < BB; ++r) { float z = logf(rowse[r]); zz += z * z; }
            *out_z = 0.001f * zz / (float)BB;
            float m = sred[0] / (float)(BB * TT);
            *out_aux = 0.01f * m * (1.f - m);
        }
        return;
    }

    // ---------- per-row stable compaction + clamp-to-last fill ----------
    const int b = blockIdx.x;
    const float* row = logits + (size_t)b * TT;

    __shared__ unsigned short s_sel[TT];
    __shared__ float          s_gw [TT];
    __shared__ int s_wsum[16];
    __shared__ int s_woff[17];

    const int t0 = tid * 8;
    float v[8];
    float4 a0 = *reinterpret_cast<const float4*>(row + t0);
    float4 a1 = *reinterpret_cast<const float4*>(row + t0 + 4);
    v[0]=a0.x; v[1]=a0.y; v[2]=a0.z; v[3]=a0.w;
    v[4]=a1.x; v[5]=a1.y; v[6]=a1.z; v[7]=a1.w;

    int c_local = 0;
    #pragma unroll
    for (int i = 0; i < 8; ++i) c_local += (v[i] >= 0.f) ? 1 : 0;

    int inc = c_local;
    #pragma unroll
    for (int off = 1; off < 64; off <<= 1) {
        int n = __shfl_up(inc, off, 64);
        if (lane >= off) inc += n;
    }
    if (lane == 63) s_wsum[wid] = inc;
    __syncthreads();
    if (tid == 0) {
        int run = 0;
        for (int i = 0; i < 16; ++i) { s_woff[i] = run; run += s_wsum[i]; }
        s_woff[16] = run;
    }
    __syncthreads();

    const int excl = s_woff[wid] + (inc - c_local);
    const int cnt  = s_woff[16];

    int o = excl;
    #pragma unroll
    for (int i = 0; i < 8; ++i) {
        if (v[i] >= 0.f) {
            s_sel[o] = (unsigned short)(t0 + i);
            s_gw [o] = 1.f / (1.f + expf(-v[i]));
            ++o;
        }
    }
    __syncthreads();

    for (int k = tid; k < max_k; k += 1024) {
        int id; float g;
        if (k < cnt)      { id = (int)s_sel[k];       g = s_gw[k]; }
        else if (cnt > 0) { id = (int)s_sel[cnt - 1]; g = s_gw[cnt - 1]; }
        else              { id = 0; g = 1.f / (1.f + expf(-row[0])); }
        out_sel[(size_t)b * max_k + k] = (float)id;
        out_gw [(size_t)b * max_k + k] = g;
    }
}

extern "C" void kernel_launch(void* const* d_in, const int* in_sizes, int n_in,
                              void* d_out, int out_size, void* d_ws, size_t ws_size,
                              hipStream_t stream)
{
    const float* x = (const float*)d_in[0];
    const float* W = (const float*)d_in[1];

    const int D  = in_sizes[1];          // 512
    const int BT = in_sizes[0] / D;      // 65536
    const int max_k = (out_size - BT - 2) / (2 * BB);

    float* out        = (float*)d_out;
    float* out_sel    = out;
    float* out_gw     = out + (size_t)BB * max_k;
    float* out_logits = out + (size_t)2 * BB * max_k;
    float* out_aux    = out + (size_t)2 * BB * max_k + BT;
    float* out_z      = out_aux + 1;

    // K1: one wave per token (proven round-1 form).
    const int grid1 = (BT + 3) / 4;      // 4 waves per 256-thread block
    logits_kernel<<<grid1, 256, 0, stream>>>(x, W, out_logits, BT);

    // K2: 8 row blocks + 1 scalar block, single launch.
    finish_kernel<<<BB + 1, 1024, 0, stream>>>(out_logits, out_sel, out_gw,
                                               out_aux, out_z, max_k);
}

// Round 4
// 32.406 us; speedup vs baseline: 2.0179x; 2.0179x over previous
//
#include <hip/hip_runtime.h>
#include <math.h>

// TokenChoiceRouter: B=8, T=8192, D=512.
// d_out (float32 flat): [selected B*max_k][gate_weights B*max_k][raw_logits B*T][aux][z]
// ws: [se f32 x16384][sg f32 x16384] per-K1-block (4-token) partials.

#define TT 8192
#define BB 8
#define NB 32          // K2 compaction blocks per row
#define SLICE 256      // tokens per K2 block slice
#define NPART 16384    // K1 blocks (= BT/4)

// K1: one wave per token (proven form) + per-block exp/sigmoid partials.
__global__ __launch_bounds__(256) void logits_kernel(
    const float* __restrict__ x, const float* __restrict__ W,
    float* __restrict__ logits,
    float* __restrict__ ws_se, float* __restrict__ ws_sg)
{
    const int tid  = threadIdx.x;
    const int lane = tid & 63;
    const int wid  = tid >> 6;
    const int tok  = blockIdx.x * 4 + wid;

    const float4* xp = reinterpret_cast<const float4*>(x + (size_t)tok * 512 + lane * 8);
    const float4* wp = reinterpret_cast<const float4*>(W + lane * 8);
    float4 x0 = xp[0]; float4 x1 = xp[1];
    float4 w0 = wp[0]; float4 w1 = wp[1];

    // f64 accumulation keeps sign decisions aligned with the f64 numpy ref.
    double acc = (double)x0.x * w0.x + (double)x0.y * w0.y
               + (double)x0.z * w0.z + (double)x0.w * w0.w
               + (double)x1.x * w1.x + (double)x1.y * w1.y
               + (double)x1.z * w1.z + (double)x1.w * w1.w;

    #pragma unroll
    for (int off = 32; off > 0; off >>= 1)
        acc += __shfl_xor(acc, off, 64);

    __shared__ float s_lg[4];
    if (lane == 0) {
        const float lg = (float)acc;
        logits[tok] = lg;
        s_lg[wid] = lg;
    }
    __syncthreads();
    if (tid == 0) {
        float se = 0.f, sg = 0.f;
        #pragma unroll
        for (int i = 0; i < 4; ++i) {
            const float lg = s_lg[i];
            se += expf(lg);
            sg += 1.f / (1.f + expf(-lg));
        }
        ws_se[blockIdx.x] = se;
        ws_sg[blockIdx.x] = sg;
    }
}

// K2: 256 compaction blocks (32/row) + 1 scalar block.
__global__ __launch_bounds__(256) void finish_kernel(
    const float* __restrict__ logits,
    const float* __restrict__ ws_se, const float* __restrict__ ws_sg,
    float* __restrict__ out_sel, float* __restrict__ out_gw,
    float* __restrict__ out_aux, float* __restrict__ out_z, int max_k)
{
    const int tid  = threadIdx.x;
    const int lane = tid & 63;
    const int wid  = tid >> 6;       // 0..3

    if (blockIdx.x == BB * NB) {
        // ---- scalar losses from ws partials (no transcendental flood) ----
        float acc8[8];
        #pragma unroll
        for (int r = 0; r < 8; ++r) {
            float s = 0.f;
            #pragma unroll
            for (int k = 0; k < 8; ++k) s += ws_se[r * 2048 + tid + 256 * k];
            acc8[r] = s;
        }
        float sgp = 0.f;
        #pragma unroll
        for (int k = 0; k < 64; ++k) sgp += ws_sg[tid + 256 * k];

        __shared__ float red[9][256];
        #pragma unroll
        for (int r = 0; r < 8; ++r) red[r][tid] = acc8[r];
        red[8][tid] = sgp;
        __syncthreads();
        for (int s = 128; s > 0; s >>= 1) {
            if (tid < s) {
                #pragma unroll
                for (int r = 0; r < 9; ++r) red[r][tid] += red[r][tid + s];
            }
            __syncthreads();
        }
        if (tid == 0) {
            float zz = 0.f;
            #pragma unroll
            for (int r = 0; r < 8; ++r) { float z = logf(red[r][0]); zz += z * z; }
            *out_z = 0.001f * zz / (float)BB;
            float m = red[8][0] / (float)(BB * TT);
            *out_aux = 0.01f * m * (1.f - m);
        }
        return;
    }

    // ---- per-row stable compaction; block owns a 256-token output slice ----
    const int row  = blockIdx.x >> 5;   // /NB
    const int part = blockIdx.x & 31;   // %NB
    const float* rowp = logits + (size_t)row * TT;

    // Thread t owns contiguous tokens [32t, 32t+32).
    const int base = 32 * tid;
    float4 v0 = *reinterpret_cast<const float4*>(rowp + base);
    float4 v1 = *reinterpret_cast<const float4*>(rowp + base + 4);
    float4 v2 = *reinterpret_cast<const float4*>(rowp + base + 8);
    float4 v3 = *reinterpret_cast<const float4*>(rowp + base + 12);
    float4 v4 = *reinterpret_cast<const float4*>(rowp + base + 16);
    float4 v5 = *reinterpret_cast<const float4*>(rowp + base + 20);
    float4 v6 = *reinterpret_cast<const float4*>(rowp + base + 24);
    float4 v7 = *reinterpret_cast<const float4*>(rowp + base + 28);

    unsigned mask = 0u;
#define CHK(f, b) mask |= ((f >= 0.f) ? 1u : 0u) << (b)
    CHK(v0.x, 0);  CHK(v0.y, 1);  CHK(v0.z, 2);  CHK(v0.w, 3);
    CHK(v1.x, 4);  CHK(v1.y, 5);  CHK(v1.z, 6);  CHK(v1.w, 7);
    CHK(v2.x, 8);  CHK(v2.y, 9);  CHK(v2.z, 10); CHK(v2.w, 11);
    CHK(v3.x, 12); CHK(v3.y, 13); CHK(v3.z, 14); CHK(v3.w, 15);
    CHK(v4.x, 16); CHK(v4.y, 17); CHK(v4.z, 18); CHK(v4.w, 19);
    CHK(v5.x, 20); CHK(v5.y, 21); CHK(v5.z, 22); CHK(v5.w, 23);
    CHK(v6.x, 24); CHK(v6.y, 25); CHK(v6.z, 26); CHK(v6.w, 27);
    CHK(v7.x, 28); CHK(v7.y, 29); CHK(v7.z, 30); CHK(v7.w, 31);
#undef CHK
    const int c_local = __popc(mask);

    // Wave inclusive scan (thread order == token order).
    int inc = c_local;
    #pragma unroll
    for (int off = 1; off < 64; off <<= 1) {
        int n = __shfl_up(inc, off, 64);
        if (lane >= off) inc += n;
    }
    __shared__ int s_wsum[4];
    __shared__ int s_last[4];
    __shared__ int s_excl[256];
    if (lane == 63) s_wsum[wid] = inc;

    int lastt = mask ? (base + 31 - __clz(mask)) : -1;
    #pragma unroll
    for (int off = 32; off > 0; off >>= 1)
        lastt = max(lastt, __shfl_xor(lastt, off, 64));
    if (lane == 0) s_last[wid] = lastt;
    __syncthreads();

    int woff = 0;
    #pragma unroll
    for (int w = 0; w < 4; ++w) if (w < wid) woff += s_wsum[w];
    const int cnt = s_wsum[0] + s_wsum[1] + s_wsum[2] + s_wsum[3];
    const int excl = woff + (inc - c_local);
    s_excl[tid] = excl;
    const int tok_last = max(max(s_last[0], s_last[1]), max(s_last[2], s_last[3]));
    __syncthreads();

    const int slice0 = s_excl[8 * part];
    const int slice1 = (part == NB - 1) ? cnt : s_excl[8 * part + 8];

    // Stage this slice's selected (tok, gw) into LDS (8 owning threads).
    __shared__ unsigned short s_tok[SLICE];
    __shared__ float          s_gwv[SLICE];
    if (tid >= 8 * part && tid < 8 * part + 8) {
        int off = excl - slice0;
#define EMIT(f, i) if ((f) >= 0.f) { s_tok[off] = (unsigned short)(base + (i)); \
                                     s_gwv[off] = 1.f / (1.f + expf(-(f))); ++off; }
        EMIT(v0.x, 0);  EMIT(v0.y, 1);  EMIT(v0.z, 2);  EMIT(v0.w, 3);
        EMIT(v1.x, 4);  EMIT(v1.y, 5);  EMIT(v1.z, 6);  EMIT(v1.w, 7);
        EMIT(v2.x, 8);  EMIT(v2.y, 9);  EMIT(v2.z, 10); EMIT(v2.w, 11);
        EMIT(v3.x, 12); EMIT(v3.y, 13); EMIT(v3.z, 14); EMIT(v3.w, 15);
        EMIT(v4.x, 16); EMIT(v4.y, 17); EMIT(v4.z, 18); EMIT(v4.w, 19);
        EMIT(v5.x, 20); EMIT(v5.y, 21); EMIT(v5.z, 22); EMIT(v5.w, 23);
        EMIT(v6.x, 24); EMIT(v6.y, 25); EMIT(v6.z, 26); EMIT(v6.w, 27);
        EMIT(v7.x, 28); EMIT(v7.y, 29); EMIT(v7.z, 30); EMIT(v7.w, 31);
#undef EMIT
    }
    __syncthreads();

    // Coalesced write of the slice's compacted entries.
    const int m = slice1 - slice0;
    if (tid < m) {
        out_sel[(size_t)row * max_k + slice0 + tid] = (float)s_tok[tid];
        out_gw [(size_t)row * max_k + slice0 + tid] = s_gwv[tid];
    }

    // Pad region [cnt, max_k): clamp to last selected (empty row -> token 0).
    const int tl = (cnt > 0) ? tok_last : 0;
    const float gw_last = 1.f / (1.f + expf(-rowp[tl]));
    for (int k = cnt + part * SLICE + tid; k < max_k; k += NB * SLICE) {
        out_sel[(size_t)row * max_k + k] = (float)tl;
        out_gw [(size_t)row * max_k + k] = gw_last;
    }
}

extern "C" void kernel_launch(void* const* d_in, const int* in_sizes, int n_in,
                              void* d_out, int out_size, void* d_ws, size_t ws_size,
                              hipStream_t stream)
{
    const float* x = (const float*)d_in[0];
    const float* W = (const float*)d_in[1];

    const int D  = in_sizes[1];          // 512
    const int BT = in_sizes[0] / D;      // 65536
    const int max_k = (out_size - BT - 2) / (2 * BB);

    float* out        = (float*)d_out;
    float* out_sel    = out;
    float* out_gw     = out + (size_t)BB * max_k;
    float* out_logits = out + (size_t)2 * BB * max_k;
    float* out_aux    = out + (size_t)2 * BB * max_k + BT;
    float* out_z      = out_aux + 1;

    float* ws_se = (float*)d_ws;
    float* ws_sg = ws_se + NPART;

    // K1: one wave per token + per-block stat partials.
    logits_kernel<<<BT / 4, 256, 0, stream>>>(x, W, out_logits, ws_se, ws_sg);

    // K2: 256 compaction blocks + 1 scalar block, single launch.
    finish_kernel<<<BB * NB + 1, 256, 0, stream>>>(out_logits, ws_se, ws_sg,
                                                   out_sel, out_gw,
                                                   out_aux, out_z, max_k);
}